// Round 1
// baseline (1018.149 us; speedup 1.0000x reference)
//
#include <hip/hip_runtime.h>
#include <hip/hip_bf16.h>

// ProbableConv2d: selection-first implementation.
// B=8, CI=128, CO=256, H=W=56, P=9, K=3.
//
// Pipeline (all on `stream`):
//   memset cnt, memset x_pad
//   k_xpose : x (NCHW f32) -> x_pad (N,58,58,CI) bf16, zero halo
//   k_wprep : kw (P,CO,CI,3,3) f32 -> W2 (P,CO,1152) bf16, k = (kh*3+kw)*128+ci
//   k_obs   : fp32 observer -> argmax path per pixel -> per-path pixel lists
//   k_conv  : per (path, co-half, pixel-tile-of-128) gathered-GEMM via MFMA bf16

typedef unsigned int u32;

#define NPIX    25088      // 8*56*56
#define XPAD_DW (8*58*58*64)
#define OFF_LIST 4096
#define OFF_XPAD 907264                      // 4096 + 9*25088*4
#define OFF_W2   (907264 + 6889472)          // + 8*58*58*128*2

__device__ __forceinline__ unsigned short f2bf(float f) {
  u32 u = __builtin_bit_cast(u32, f);
  u32 r = (u + 0x7FFFu + ((u >> 16) & 1u)) >> 16;
  return (unsigned short)r;
}

#define GLDS16(g, l)                                                        \
  __builtin_amdgcn_global_load_lds(                                         \
      (const __attribute__((address_space(1))) u32*)(g),                    \
      (__attribute__((address_space(3))) u32*)(l), 16, 0, 0)

typedef __attribute__((ext_vector_type(8))) short bf16x8;
typedef __attribute__((ext_vector_type(4))) float f32x4;

// ---------------------------------------------------------------- x -> NHWC bf16 pad
__global__ __launch_bounds__(256) void k_xpose(const float* __restrict__ x,
                                               u32* __restrict__ xpad) {
  int bh = blockIdx.x;                 // 0..447 = b*56+h
  int b = bh / 56, h = bh - b * 56;
  int cp = threadIdx.x & 63;           // ci pair
  int wq = threadIdx.x >> 6;
  const float* xb = x + (size_t)(b * 128 + 2 * cp) * 3136 + h * 56;
  u32* ob = xpad + (size_t)(b * 58 + h + 1) * 58 * 64 + 64 + cp;  // (w+1)*64 added in loop
  for (int w = wq; w < 56; w += 4) {
    float f0 = xb[w];
    float f1 = xb[3136 + w];
    ob[w * 64] = (u32)f2bf(f0) | ((u32)f2bf(f1) << 16);
  }
}

// ---------------------------------------------------------------- kw -> [p][co][k] bf16
__global__ __launch_bounds__(256) void k_wprep(const float* __restrict__ kw,
                                               u32* __restrict__ w2) {
  int t = blockIdx.x * 256 + threadIdx.x;  // 0..1327103 == out dword index
  int cp = t & 63;
  int r = t >> 6;             // pco*9 + tap
  int tap = r % 9;
  int pco = r / 9;
  const float* s = kw + ((size_t)pco * 128 + 2 * cp) * 9 + tap;
  w2[t] = (u32)f2bf(s[0]) | ((u32)f2bf(s[9]) << 16);
}

// ---------------------------------------------------------------- observer + argmax + compaction
__global__ __launch_bounds__(256, 2) void k_obs(
    const float* __restrict__ x, const float* __restrict__ ow1,
    const float* __restrict__ ob1, const float* __restrict__ ow2,
    const float* __restrict__ ob2, int* __restrict__ cnt,
    int* __restrict__ list) {
  int px = threadIdx.x & 63;         // pixel within block
  int dq = threadIdx.x >> 6;         // d-quarter (wave-uniform)
  int pix = blockIdx.x * 64 + px;    // block stays within one b (3136 % 64 == 0)
  int b = pix / 3136, s = pix - b * 3136;
  const float* xb = x + (size_t)b * 401408 + s;
  float xr[128];
#pragma unroll
  for (int ci = 0; ci < 128; ++ci) xr[ci] = xb[ci * 3136];

  float sc[9];
#pragma unroll
  for (int p = 0; p < 9; ++p) sc[p] = 0.f;

  int d0 = dq * 32;
  for (int dd = 0; dd < 32; dd += 8) {
    float acc[8];
#pragma unroll
    for (int j = 0; j < 8; ++j) acc[j] = ob1[d0 + dd + j];
#pragma unroll
    for (int ci = 0; ci < 128; ++ci) {
      float xv = xr[ci];
#pragma unroll
      for (int j = 0; j < 8; ++j)
        acc[j] = fmaf(ow1[(d0 + dd + j) * 128 + ci], xv, acc[j]);
    }
#pragma unroll
    for (int j = 0; j < 8; ++j) {
      float tv = tanhf(acc[j]);
#pragma unroll
      for (int p = 0; p < 9; ++p)
        sc[p] = fmaf(ow2[p * 128 + d0 + dd + j], tv, sc[p]);
    }
  }

  __shared__ float red[4][64][9];
#pragma unroll
  for (int p = 0; p < 9; ++p) red[dq][px][p] = sc[p];
  __syncthreads();
  if (dq == 0) {
    float best = 0.f;
    int bi = 0;
#pragma unroll
    for (int p = 0; p < 9; ++p) {
      float v = red[0][px][p] + red[1][px][p] + red[2][px][p] + red[3][px][p] + ob2[p];
      if (p == 0) { best = v; }
      else if (v > best) { best = v; bi = p; }   // strict > : first max, matches argmax
    }
    int slot = atomicAdd(&cnt[bi], 1);
    list[bi * NPIX + slot] = pix;
  }
}

// ---------------------------------------------------------------- gathered GEMM conv
__global__ __launch_bounds__(256, 3) void k_conv(
    const int* __restrict__ cnt, const int* __restrict__ list,
    const char* __restrict__ xpadB, const char* __restrict__ w2B,
    const float* __restrict__ kb, float* __restrict__ out) {
  __shared__ short Wlds[2][4096];  // [buf][co(128) x k(32)]
  __shared__ short Plds[2][4096];  // [buf][px(128) x k(32)]
  __shared__ int offsB[128], outSB[128];
  __shared__ float kbl[128];

  int bid = blockIdx.x;
  int half = bid & 1, tb = bid >> 1;
  int p = -1, cntp = 0;
  for (int pp = 0; pp < 9; ++pp) {     // uniform scan: block -> (path, tile)
    int c = cnt[pp];
    int tt = (c + 127) >> 7;
    if (p < 0) {
      if (tb < tt) { p = pp; cntp = c; }
      else tb -= tt;
    }
  }
  if (p < 0) return;
  int nbase = tb * 128;
  int tid = threadIdx.x;

  if (tid < 128) {
    int g = nbase + tid;
    int pixid = list[p * NPIX + (g < cntp ? g : nbase)];
    int b = pixid / 3136, s = pixid - b * 3136;
    int h = s / 56, w = s - h * 56;
    offsB[tid] = ((b * 58 + h) * 58 + w) * 256;  // byte offset of tap(0,0) in x_pad
    outSB[tid] = b * 802816 + s;
    kbl[tid] = kb[p * 256 + half * 128 + tid];
  }
  __syncthreads();

  int seg16 = (tid & 3) * 16;
  int na = tid >> 2;                       // 0..63
  int offP0 = offsB[na] + seg16;
  int offP1 = offsB[64 + na] + seg16;
  const char* wrow = w2B + (size_t)(p * 256 + half * 128) * 2304;
  const char* wp0 = wrow + na * 2304 + seg16;
  const char* wp1 = wrow + (size_t)(64 + na) * 2304 + seg16;

  auto stage = [&](int c, int q) {
    int tap = c >> 2, kc = c & 3;
    int wko = tap * 256 + kc * 64;                          // bytes within W row
    int tapoff = ((tap / 3) * 58 + (tap % 3)) * 256 + kc * 64;  // bytes within x_pad
    GLDS16(wp0 + wko, &Wlds[q][tid * 8]);
    GLDS16(wp1 + wko, &Wlds[q][2048 + tid * 8]);
    GLDS16(xpadB + (size_t)(offP0 + tapoff), &Plds[q][tid * 8]);
    GLDS16(xpadB + (size_t)(offP1 + tapoff), &Plds[q][2048 + tid * 8]);
  };

  f32x4 acc[4][4];
#pragma unroll
  for (int mt = 0; mt < 4; ++mt)
#pragma unroll
    for (int nt = 0; nt < 4; ++nt) acc[mt][nt] = (f32x4)0.f;

  int lane = tid & 63, wave = tid >> 6;
  int wm = wave >> 1, wn = wave & 1;
  int mrow = wm * 64 + (lane & 15);
  int nrow = wn * 64 + (lane & 15);
  int kg8 = (lane >> 4) * 8;

  stage(0, 0);
  for (int c = 0; c < 36; ++c) {
    __syncthreads();                       // drains stage(c); protects buffer reuse
    if (c + 1 < 36) stage(c + 1, (c + 1) & 1);
    int q = c & 1;
    bf16x8 af[4], bfr[4];
#pragma unroll
    for (int mt = 0; mt < 4; ++mt)
      af[mt] = *(const bf16x8*)&Wlds[q][(mrow + mt * 16) * 32 + kg8];
#pragma unroll
    for (int nt = 0; nt < 4; ++nt)
      bfr[nt] = *(const bf16x8*)&Plds[q][(nrow + nt * 16) * 32 + kg8];
#pragma unroll
    for (int mt = 0; mt < 4; ++mt)
#pragma unroll
      for (int nt = 0; nt < 4; ++nt)
        acc[mt][nt] = __builtin_amdgcn_mfma_f32_16x16x32_bf16(
            af[mt], bfr[nt], acc[mt][nt], 0, 0, 0);
  }

  // epilogue: D col = lane&15 (pixel), row = (lane>>4)*4 + r (co)
  int col = lane & 15, quad = lane >> 4;
#pragma unroll
  for (int nt = 0; nt < 4; ++nt) {
    int n = wn * 64 + nt * 16 + col;
    bool valid = (nbase + n) < cntp;
    int ob = outSB[n];
#pragma unroll
    for (int mt = 0; mt < 4; ++mt) {
#pragma unroll
      for (int r = 0; r < 4; ++r) {
        int co_l = wm * 64 + mt * 16 + quad * 4 + r;
        float v = acc[mt][nt][r] + kbl[co_l];
        v = v > 0.f ? v : 0.f;
        if (valid) out[ob + (half * 128 + co_l) * 3136] = v;
      }
    }
  }
}

// ----------------------------------------------------------------
extern "C" void kernel_launch(void* const* d_in, const int* in_sizes, int n_in,
                              void* d_out, int out_size, void* d_ws, size_t ws_size,
                              hipStream_t stream) {
  const float* x   = (const float*)d_in[0];
  const float* kw  = (const float*)d_in[1];
  const float* kb  = (const float*)d_in[2];
  const float* ow1 = (const float*)d_in[3];
  const float* ob1 = (const float*)d_in[4];
  const float* ow2 = (const float*)d_in[5];
  const float* ob2 = (const float*)d_in[6];
  float* out = (float*)d_out;
  char* ws = (char*)d_ws;

  int* cnt  = (int*)(ws);
  int* list = (int*)(ws + OFF_LIST);
  u32* xpad = (u32*)(ws + OFF_XPAD);
  u32* w2   = (u32*)(ws + OFF_W2);

  hipMemsetAsync(cnt, 0, 64, stream);
  hipMemsetAsync(xpad, 0, (size_t)XPAD_DW * 4, stream);  // zero halo (interior overwritten)

  k_xpose<<<448, 256, 0, stream>>>(x, xpad);
  k_wprep<<<5184, 256, 0, stream>>>(kw, w2);
  k_obs<<<392, 256, 0, stream>>>(x, ow1, ob1, ow2, ob2, cnt, list);
  k_conv<<<408, 256, 0, stream>>>(cnt, list, (const char*)xpad, (const char*)w2,
                                  kb, out);
}

// Round 3
// 540.636 us; speedup vs baseline: 1.8832x; 1.8832x over previous
//
#include <hip/hip_runtime.h>
#include <hip/hip_bf16.h>

// ProbableConv2d: selection-first implementation.
// B=8, CI=128, CO=256, H=W=56, P=9, K=3.
//
// Pipeline (all on `stream`):
//   memset cnt, memset x_pad
//   k_xpose : x (NCHW f32) -> x_pad (N,58,58,CI) bf16, zero halo
//   k_wprep : kw (P,CO,CI,3,3) f32 -> W2 (P,CO,1152) bf16, k = (kh*3+kw)*128+ci
//   k_obs   : fp32 observer -> argmax path per pixel -> per-path pixel lists
//             (R2: hidden dim is 128 (=CO//2), NOT 64 — R1 computed scores
//              from half the hidden layer with wrong ow2 stride -> wrong argmax.
//              All loops indexing h[] are FULLY unrolled so h stays in VGPRs;
//              R0 version spilled under a 128-VGPR launch_bounds cap -> 862us.)
//   k_conv  : per (path, co-half, pixel-tile-of-128) gathered-GEMM via MFMA bf16

typedef unsigned int u32;

#define NPIX    25088      // 8*56*56
#define XPAD_DW (8*58*58*64)
#define OFF_LIST 4096
#define OFF_XPAD 907264                      // 4096 + 9*25088*4
#define OFF_W2   (907264 + 6889472)          // + 8*58*58*128*2

__device__ __forceinline__ unsigned short f2bf(float f) {
  u32 u = __builtin_bit_cast(u32, f);
  u32 r = (u + 0x7FFFu + ((u >> 16) & 1u)) >> 16;
  return (unsigned short)r;
}

#define GLDS16(g, l)                                                        \
  __builtin_amdgcn_global_load_lds(                                         \
      (const __attribute__((address_space(1))) u32*)(g),                    \
      (__attribute__((address_space(3))) u32*)(l), 16, 0, 0)

typedef __attribute__((ext_vector_type(8))) short bf16x8;
typedef __attribute__((ext_vector_type(4))) float f32x4;

// ---------------------------------------------------------------- x -> NHWC bf16 pad
__global__ __launch_bounds__(256) void k_xpose(const float* __restrict__ x,
                                               u32* __restrict__ xpad) {
  int bh = blockIdx.x;                 // 0..447 = b*56+h
  int b = bh / 56, h = bh - b * 56;
  int cp = threadIdx.x & 63;           // ci pair
  int wq = threadIdx.x >> 6;
  const float* xb = x + (size_t)(b * 128 + 2 * cp) * 3136 + h * 56;
  u32* ob = xpad + (size_t)(b * 58 + h + 1) * 58 * 64 + 64 + cp;  // (w+1)*64 added in loop
  for (int w = wq; w < 56; w += 4) {
    float f0 = xb[w];
    float f1 = xb[3136 + w];
    ob[w * 64] = (u32)f2bf(f0) | ((u32)f2bf(f1) << 16);
  }
}

// ---------------------------------------------------------------- kw -> [p][co][k] bf16
__global__ __launch_bounds__(256) void k_wprep(const float* __restrict__ kw,
                                               u32* __restrict__ w2) {
  int t = blockIdx.x * 256 + threadIdx.x;  // 0..1327103 == out dword index
  int cp = t & 63;
  int r = t >> 6;             // pco*9 + tap
  int tap = r % 9;
  int pco = r / 9;
  const float* s = kw + ((size_t)pco * 128 + 2 * cp) * 9 + tap;
  w2[t] = (u32)f2bf(s[0]) | ((u32)f2bf(s[9]) << 16);
}

// ---------------------------------------------------------------- observer + argmax + compaction
// 1 thread = 1 pixel. h[128] accumulators in VGPRs (all h-indexing loops fully
// unrolled); ow1/ow2 addresses are loop-uniform -> scalar s_load_dwordx4.
__global__ __launch_bounds__(64) void k_obs(
    const float* __restrict__ x, const float* __restrict__ ow1,
    const float* __restrict__ ob1, const float* __restrict__ ow2,
    const float* __restrict__ ob2, int* __restrict__ cnt,
    int* __restrict__ list) {
  int pix = blockIdx.x * 64 + threadIdx.x;   // 392*64 == 25088 exactly
  int b = pix / 3136, s = pix - b * 3136;
  const float* xb = x + (size_t)b * 401408 + s;

  float h[128];
#pragma unroll
  for (int d = 0; d < 128; ++d) h[d] = ob1[d];

  for (int cc = 0; cc < 128; cc += 4) {    // dynamic loop: only ci is chunked
    float xc0 = xb[(size_t)cc * 3136];
    float xc1 = xb[(size_t)(cc + 1) * 3136];
    float xc2 = xb[(size_t)(cc + 2) * 3136];
    float xc3 = xb[(size_t)(cc + 3) * 3136];
#pragma unroll
    for (int d = 0; d < 128; ++d) {
      const float* wr = ow1 + d * 128 + cc;  // uniform -> s_load_dwordx4
      float a = h[d];
      a = fmaf(wr[0], xc0, a);
      a = fmaf(wr[1], xc1, a);
      a = fmaf(wr[2], xc2, a);
      a = fmaf(wr[3], xc3, a);
      h[d] = a;
    }
  }

#pragma unroll
  for (int d = 0; d < 128; ++d) h[d] = tanhf(h[d]);

  float best = 0.f;
  int bi = 0;
#pragma unroll
  for (int p = 0; p < 9; ++p) {
    float sc = ob2[p];
    const float* wr = ow2 + p * 128;
#pragma unroll
    for (int d = 0; d < 128; ++d) sc = fmaf(wr[d], h[d], sc);
    if (p == 0 || sc > best) { best = sc; bi = p; }  // strict >: first max (np argmax)
  }

  int slot = atomicAdd(&cnt[bi], 1);
  list[bi * NPIX + slot] = pix;
}

// ---------------------------------------------------------------- gathered GEMM conv
__global__ __launch_bounds__(256, 3) void k_conv(
    const int* __restrict__ cnt, const int* __restrict__ list,
    const char* __restrict__ xpadB, const char* __restrict__ w2B,
    const float* __restrict__ kb, float* __restrict__ out) {
  __shared__ short Wlds[2][4096];  // [buf][co(128) x k(32)]
  __shared__ short Plds[2][4096];  // [buf][px(128) x k(32)]
  __shared__ int offsB[128], outSB[128];
  __shared__ float kbl[128];

  int bid = blockIdx.x;
  int half = bid & 1, tb = bid >> 1;
  int p = -1, cntp = 0;
  for (int pp = 0; pp < 9; ++pp) {     // uniform scan: block -> (path, tile)
    int c = cnt[pp];
    int tt = (c + 127) >> 7;
    if (p < 0) {
      if (tb < tt) { p = pp; cntp = c; }
      else tb -= tt;
    }
  }
  if (p < 0) return;
  int nbase = tb * 128;
  int tid = threadIdx.x;

  if (tid < 128) {
    int g = nbase + tid;
    int pixid = list[p * NPIX + (g < cntp ? g : nbase)];
    int b = pixid / 3136, s = pixid - b * 3136;
    int h = s / 56, w = s - h * 56;
    offsB[tid] = ((b * 58 + h) * 58 + w) * 256;  // byte offset of tap(0,0) in x_pad
    outSB[tid] = b * 802816 + s;
    kbl[tid] = kb[p * 256 + half * 128 + tid];
  }
  __syncthreads();

  int seg16 = (tid & 3) * 16;
  int na = tid >> 2;                       // 0..63
  int offP0 = offsB[na] + seg16;
  int offP1 = offsB[64 + na] + seg16;
  const char* wrow = w2B + (size_t)(p * 256 + half * 128) * 2304;
  const char* wp0 = wrow + na * 2304 + seg16;
  const char* wp1 = wrow + (size_t)(64 + na) * 2304 + seg16;

  auto stage = [&](int c, int q) {
    int tap = c >> 2, kc = c & 3;
    int wko = tap * 256 + kc * 64;                          // bytes within W row
    int tapoff = ((tap / 3) * 58 + (tap % 3)) * 256 + kc * 64;  // bytes within x_pad
    GLDS16(wp0 + wko, &Wlds[q][tid * 8]);
    GLDS16(wp1 + wko, &Wlds[q][2048 + tid * 8]);
    GLDS16(xpadB + (size_t)(offP0 + tapoff), &Plds[q][tid * 8]);
    GLDS16(xpadB + (size_t)(offP1 + tapoff), &Plds[q][2048 + tid * 8]);
  };

  f32x4 acc[4][4];
#pragma unroll
  for (int mt = 0; mt < 4; ++mt)
#pragma unroll
    for (int nt = 0; nt < 4; ++nt) acc[mt][nt] = (f32x4)0.f;

  int lane = tid & 63, wave = tid >> 6;
  int wm = wave >> 1, wn = wave & 1;
  int mrow = wm * 64 + (lane & 15);
  int nrow = wn * 64 + (lane & 15);
  int kg8 = (lane >> 4) * 8;

  stage(0, 0);
  for (int c = 0; c < 36; ++c) {
    __syncthreads();                       // drains stage(c); protects buffer reuse
    if (c + 1 < 36) stage(c + 1, (c + 1) & 1);
    int q = c & 1;
    bf16x8 af[4], bfr[4];
#pragma unroll
    for (int mt = 0; mt < 4; ++mt)
      af[mt] = *(const bf16x8*)&Wlds[q][(mrow + mt * 16) * 32 + kg8];
#pragma unroll
    for (int nt = 0; nt < 4; ++nt)
      bfr[nt] = *(const bf16x8*)&Plds[q][(nrow + nt * 16) * 32 + kg8];
#pragma unroll
    for (int mt = 0; mt < 4; ++mt)
#pragma unroll
      for (int nt = 0; nt < 4; ++nt)
        acc[mt][nt] = __builtin_amdgcn_mfma_f32_16x16x32_bf16(
            af[mt], bfr[nt], acc[mt][nt], 0, 0, 0);
  }

  // epilogue: D col = lane&15 (pixel), row = (lane>>4)*4 + r (co)
  int col = lane & 15, quad = lane >> 4;
#pragma unroll
  for (int nt = 0; nt < 4; ++nt) {
    int n = wn * 64 + nt * 16 + col;
    bool valid = (nbase + n) < cntp;
    int ob = outSB[n];
#pragma unroll
    for (int mt = 0; mt < 4; ++mt) {
#pragma unroll
      for (int r = 0; r < 4; ++r) {
        int co_l = wm * 64 + mt * 16 + quad * 4 + r;
        float v = acc[mt][nt][r] + kbl[co_l];
        v = v > 0.f ? v : 0.f;
        if (valid) out[ob + (half * 128 + co_l) * 3136] = v;
      }
    }
  }
}

// ----------------------------------------------------------------
extern "C" void kernel_launch(void* const* d_in, const int* in_sizes, int n_in,
                              void* d_out, int out_size, void* d_ws, size_t ws_size,
                              hipStream_t stream) {
  const float* x   = (const float*)d_in[0];
  const float* kw  = (const float*)d_in[1];
  const float* kb  = (const float*)d_in[2];
  const float* ow1 = (const float*)d_in[3];
  const float* ob1 = (const float*)d_in[4];
  const float* ow2 = (const float*)d_in[5];
  const float* ob2 = (const float*)d_in[6];
  float* out = (float*)d_out;
  char* ws = (char*)d_ws;

  int* cnt  = (int*)(ws);
  int* list = (int*)(ws + OFF_LIST);
  u32* xpad = (u32*)(ws + OFF_XPAD);
  u32* w2   = (u32*)(ws + OFF_W2);

  hipMemsetAsync(cnt, 0, 64, stream);
  hipMemsetAsync(xpad, 0, (size_t)XPAD_DW * 4, stream);  // zero halo (interior overwritten)

  k_xpose<<<448, 256, 0, stream>>>(x, xpad);
  k_wprep<<<5184, 256, 0, stream>>>(kw, w2);
  k_obs<<<392, 64, 0, stream>>>(x, ow1, ob1, ow2, ob2, cnt, list);
  k_conv<<<408, 256, 0, stream>>>(cnt, list, (const char*)xpad, (const char*)w2,
                                  kb, out);
}

// Round 4
// 233.322 us; speedup vs baseline: 4.3637x; 2.3171x over previous
//
#include <hip/hip_runtime.h>
#include <hip/hip_bf16.h>

// ProbableConv2d: selection-first implementation.
// B=8, CI=128, CO=256, H=W=56, P=9, K=3.
//
// Pipeline (all on `stream`):
//   memset cnt, memset x_pad
//   k_xpose : x (NCHW f32) -> x_pad (N,58,58,CI) bf16, zero halo
//   k_wprep : kw (P,CO,CI,3,3) f32 -> W2 (P,CO,1152) bf16, k = (kh*3+kw)*128+ci
//   k_obs   : fp32 observer -> argmax path per pixel -> per-path pixel lists
//             (R4: 512-thr block = 64 px x 8 d-groups. R3's 1-thread-per-pixel
//              was only 392 waves chip-wide -> VALUBusy 6%, 410us. d-group ==
//              wave keeps ow1 addrs wave-uniform (scalar loads); h[16] fully
//              unrolled stays in VGPRs; LDS red[8][64][9] fp32 reduction;
//              per-block LDS count aggregation -> 9 global atomics/block.)
//   k_conv  : per (path, co-half, pixel-tile-of-128) gathered-GEMM via MFMA bf16

typedef unsigned int u32;

#define NPIX    25088      // 8*56*56
#define XPAD_DW (8*58*58*64)
#define OFF_LIST 4096
#define OFF_XPAD 907264                      // 4096 + 9*25088*4
#define OFF_W2   (907264 + 6889472)          // + 8*58*58*128*2

__device__ __forceinline__ unsigned short f2bf(float f) {
  u32 u = __builtin_bit_cast(u32, f);
  u32 r = (u + 0x7FFFu + ((u >> 16) & 1u)) >> 16;
  return (unsigned short)r;
}

#define GLDS16(g, l)                                                        \
  __builtin_amdgcn_global_load_lds(                                         \
      (const __attribute__((address_space(1))) u32*)(g),                    \
      (__attribute__((address_space(3))) u32*)(l), 16, 0, 0)

typedef __attribute__((ext_vector_type(8))) short bf16x8;
typedef __attribute__((ext_vector_type(4))) float f32x4;

// ---------------------------------------------------------------- x -> NHWC bf16 pad
__global__ __launch_bounds__(256) void k_xpose(const float* __restrict__ x,
                                               u32* __restrict__ xpad) {
  int bh = blockIdx.x;                 // 0..447 = b*56+h
  int b = bh / 56, h = bh - b * 56;
  int cp = threadIdx.x & 63;           // ci pair
  int wq = threadIdx.x >> 6;
  const float* xb = x + (size_t)(b * 128 + 2 * cp) * 3136 + h * 56;
  u32* ob = xpad + (size_t)(b * 58 + h + 1) * 58 * 64 + 64 + cp;  // (w+1)*64 added in loop
  for (int w = wq; w < 56; w += 4) {
    float f0 = xb[w];
    float f1 = xb[3136 + w];
    ob[w * 64] = (u32)f2bf(f0) | ((u32)f2bf(f1) << 16);
  }
}

// ---------------------------------------------------------------- kw -> [p][co][k] bf16
__global__ __launch_bounds__(256) void k_wprep(const float* __restrict__ kw,
                                               u32* __restrict__ w2) {
  int t = blockIdx.x * 256 + threadIdx.x;  // 0..1327103 == out dword index
  int cp = t & 63;
  int r = t >> 6;             // pco*9 + tap
  int tap = r % 9;
  int pco = r / 9;
  const float* s = kw + ((size_t)pco * 128 + 2 * cp) * 9 + tap;
  w2[t] = (u32)f2bf(s[0]) | ((u32)f2bf(s[9]) << 16);
}

// ---------------------------------------------------------------- observer + argmax + compaction
__global__ __launch_bounds__(512) void k_obs(
    const float* __restrict__ x, const float* __restrict__ ow1,
    const float* __restrict__ ob1, const float* __restrict__ ow2,
    const float* __restrict__ ob2, int* __restrict__ cnt,
    int* __restrict__ list) {
  __shared__ float red[8][64][9];   // stride-9 dwords -> 2-way bank alias (free)
  __shared__ int lcnt[9], lbase[9];

  int px = threadIdx.x & 63;        // pixel within block tile
  int dg = threadIdx.x >> 6;        // d-group == wave id (wave-uniform)
  int pix = blockIdx.x * 64 + px;   // 392*64 == 25088; block stays in one b
  int b = pix / 3136, s = pix - b * 3136;
  const float* xb = x + (size_t)b * 401408 + s;

  if (threadIdx.x < 9) lcnt[threadIdx.x] = 0;

  float h[16];
  const float* o1 = ob1 + dg * 16;
#pragma unroll
  for (int i = 0; i < 16; ++i) h[i] = o1[i];

  for (int cc = 0; cc < 128; cc += 8) {    // only dynamic loop
    float xc[8];
#pragma unroll
    for (int j = 0; j < 8; ++j) xc[j] = xb[(size_t)(cc + j) * 3136];
#pragma unroll
    for (int i = 0; i < 16; ++i) {
      const float* wr = ow1 + (dg * 16 + i) * 128 + cc;  // uniform -> s_load
      float a = h[i];
#pragma unroll
      for (int j = 0; j < 8; ++j) a = fmaf(wr[j], xc[j], a);
      h[i] = a;
    }
  }

#pragma unroll
  for (int i = 0; i < 16; ++i) h[i] = tanhf(h[i]);

#pragma unroll
  for (int p = 0; p < 9; ++p) {
    float sc = 0.f;
    const float* wr = ow2 + p * 128 + dg * 16;
#pragma unroll
    for (int i = 0; i < 16; ++i) sc = fmaf(wr[i], h[i], sc);
    red[dg][px][p] = sc;
  }
  __syncthreads();

  int bi = 0, slot = 0;
  if (dg == 0) {
    float best = 0.f;
#pragma unroll
    for (int p = 0; p < 9; ++p) {
      float v = ob2[p];
#pragma unroll
      for (int g = 0; g < 8; ++g) v += red[g][px][p];  // ascending-d chunk order
      if (p == 0 || v > best) { best = v; bi = p; }    // strict >: np argmax
    }
    slot = atomicAdd(&lcnt[bi], 1);   // LDS atomic
  }
  __syncthreads();
  if (threadIdx.x < 9)
    lbase[threadIdx.x] = atomicAdd(&cnt[threadIdx.x], lcnt[threadIdx.x]);
  __syncthreads();
  if (dg == 0) list[bi * NPIX + lbase[bi] + slot] = pix;
}

// ---------------------------------------------------------------- gathered GEMM conv
__global__ __launch_bounds__(256, 3) void k_conv(
    const int* __restrict__ cnt, const int* __restrict__ list,
    const char* __restrict__ xpadB, const char* __restrict__ w2B,
    const float* __restrict__ kb, float* __restrict__ out) {
  __shared__ short Wlds[2][4096];  // [buf][co(128) x k(32)]
  __shared__ short Plds[2][4096];  // [buf][px(128) x k(32)]
  __shared__ int offsB[128], outSB[128];
  __shared__ float kbl[128];

  int bid = blockIdx.x;
  int half = bid & 1, tb = bid >> 1;
  int p = -1, cntp = 0;
  for (int pp = 0; pp < 9; ++pp) {     // uniform scan: block -> (path, tile)
    int c = cnt[pp];
    int tt = (c + 127) >> 7;
    if (p < 0) {
      if (tb < tt) { p = pp; cntp = c; }
      else tb -= tt;
    }
  }
  if (p < 0) return;
  int nbase = tb * 128;
  int tid = threadIdx.x;

  if (tid < 128) {
    int g = nbase + tid;
    int pixid = list[p * NPIX + (g < cntp ? g : nbase)];
    int b = pixid / 3136, s = pixid - b * 3136;
    int h = s / 56, w = s - h * 56;
    offsB[tid] = ((b * 58 + h) * 58 + w) * 256;  // byte offset of tap(0,0) in x_pad
    outSB[tid] = b * 802816 + s;
    kbl[tid] = kb[p * 256 + half * 128 + tid];
  }
  __syncthreads();

  int seg16 = (tid & 3) * 16;
  int na = tid >> 2;                       // 0..63
  int offP0 = offsB[na] + seg16;
  int offP1 = offsB[64 + na] + seg16;
  const char* wrow = w2B + (size_t)(p * 256 + half * 128) * 2304;
  const char* wp0 = wrow + na * 2304 + seg16;
  const char* wp1 = wrow + (size_t)(64 + na) * 2304 + seg16;

  auto stage = [&](int c, int q) {
    int tap = c >> 2, kc = c & 3;
    int wko = tap * 256 + kc * 64;                          // bytes within W row
    int tapoff = ((tap / 3) * 58 + (tap % 3)) * 256 + kc * 64;  // bytes within x_pad
    GLDS16(wp0 + wko, &Wlds[q][tid * 8]);
    GLDS16(wp1 + wko, &Wlds[q][2048 + tid * 8]);
    GLDS16(xpadB + (size_t)(offP0 + tapoff), &Plds[q][tid * 8]);
    GLDS16(xpadB + (size_t)(offP1 + tapoff), &Plds[q][2048 + tid * 8]);
  };

  f32x4 acc[4][4];
#pragma unroll
  for (int mt = 0; mt < 4; ++mt)
#pragma unroll
    for (int nt = 0; nt < 4; ++nt) acc[mt][nt] = (f32x4)0.f;

  int lane = tid & 63, wave = tid >> 6;
  int wm = wave >> 1, wn = wave & 1;
  int mrow = wm * 64 + (lane & 15);
  int nrow = wn * 64 + (lane & 15);
  int kg8 = (lane >> 4) * 8;

  stage(0, 0);
  for (int c = 0; c < 36; ++c) {
    __syncthreads();                       // drains stage(c); protects buffer reuse
    if (c + 1 < 36) stage(c + 1, (c + 1) & 1);
    int q = c & 1;
    bf16x8 af[4], bfr[4];
#pragma unroll
    for (int mt = 0; mt < 4; ++mt)
      af[mt] = *(const bf16x8*)&Wlds[q][(mrow + mt * 16) * 32 + kg8];
#pragma unroll
    for (int nt = 0; nt < 4; ++nt)
      bfr[nt] = *(const bf16x8*)&Plds[q][(nrow + nt * 16) * 32 + kg8];
#pragma unroll
    for (int mt = 0; mt < 4; ++mt)
#pragma unroll
      for (int nt = 0; nt < 4; ++nt)
        acc[mt][nt] = __builtin_amdgcn_mfma_f32_16x16x32_bf16(
            af[mt], bfr[nt], acc[mt][nt], 0, 0, 0);
  }

  // epilogue: D col = lane&15 (pixel), row = (lane>>4)*4 + r (co)
  int col = lane & 15, quad = lane >> 4;
#pragma unroll
  for (int nt = 0; nt < 4; ++nt) {
    int n = wn * 64 + nt * 16 + col;
    bool valid = (nbase + n) < cntp;
    int ob = outSB[n];
#pragma unroll
    for (int mt = 0; mt < 4; ++mt) {
#pragma unroll
      for (int r = 0; r < 4; ++r) {
        int co_l = wm * 64 + mt * 16 + quad * 4 + r;
        float v = acc[mt][nt][r] + kbl[co_l];
        v = v > 0.f ? v : 0.f;
        if (valid) out[ob + (half * 128 + co_l) * 3136] = v;
      }
    }
  }
}

// ----------------------------------------------------------------
extern "C" void kernel_launch(void* const* d_in, const int* in_sizes, int n_in,
                              void* d_out, int out_size, void* d_ws, size_t ws_size,
                              hipStream_t stream) {
  const float* x   = (const float*)d_in[0];
  const float* kw  = (const float*)d_in[1];
  const float* kb  = (const float*)d_in[2];
  const float* ow1 = (const float*)d_in[3];
  const float* ob1 = (const float*)d_in[4];
  const float* ow2 = (const float*)d_in[5];
  const float* ob2 = (const float*)d_in[6];
  float* out = (float*)d_out;
  char* ws = (char*)d_ws;

  int* cnt  = (int*)(ws);
  int* list = (int*)(ws + OFF_LIST);
  u32* xpad = (u32*)(ws + OFF_XPAD);
  u32* w2   = (u32*)(ws + OFF_W2);

  hipMemsetAsync(cnt, 0, 64, stream);
  hipMemsetAsync(xpad, 0, (size_t)XPAD_DW * 4, stream);  // zero halo (interior overwritten)

  k_xpose<<<448, 256, 0, stream>>>(x, xpad);
  k_wprep<<<5184, 256, 0, stream>>>(kw, w2);
  k_obs<<<392, 512, 0, stream>>>(x, ow1, ob1, ow2, ob2, cnt, list);
  k_conv<<<408, 256, 0, stream>>>(cnt, list, (const char*)xpad, (const char*)w2,
                                  kb, out);
}

// Round 5
// 181.056 us; speedup vs baseline: 5.6234x; 1.2887x over previous
//
#include <hip/hip_runtime.h>
#include <hip/hip_bf16.h>

// ProbableConv2d: selection-first implementation.
// B=8, CI=128, CO=256, H=W=56, P=9, K=3.
//
// 3 dispatches:
//   memset cnt (64 B)
//   k_front : fused — [obs blocks 0..391] fp32 observer -> argmax -> per-path
//             pixel lists; [392..839] x -> x_pad NHWC bf16 (incl. halo cols);
//             [840..855] zero halo rows; [856..1111] kw -> W2 bf16.
//             Obs blocks first: they're the long pole and depend on nothing.
//             R5: ow1/ow2 addresses go through readfirstlane(dg) -> provably
//             wave-uniform -> s_load_dwordx8 on scalar pipe. R4 left them as
//             per-lane global_loads (SGPR_Count=32!) -> VMEM-issue-bound,
//             VALUBusy 22%, 77us.
//   k_conv  : per (path, co-half, pixel-tile-of-128) gathered-GEMM, MFMA bf16.

typedef unsigned int u32;

#define NPIX    25088      // 8*56*56
#define XPAD_DW (8*58*58*64)
#define OFF_LIST 4096
#define OFF_XPAD 907264                      // 4096 + 9*25088*4
#define OFF_W2   (907264 + 6889472)          // + 8*58*58*128*2

__device__ __forceinline__ unsigned short f2bf(float f) {
  u32 u = __builtin_bit_cast(u32, f);
  u32 r = (u + 0x7FFFu + ((u >> 16) & 1u)) >> 16;
  return (unsigned short)r;
}

#define GLDS16(g, l)                                                        \
  __builtin_amdgcn_global_load_lds(                                         \
      (const __attribute__((address_space(1))) u32*)(g),                    \
      (__attribute__((address_space(3))) u32*)(l), 16, 0, 0)

typedef __attribute__((ext_vector_type(8))) short bf16x8;
typedef __attribute__((ext_vector_type(4))) float f32x4;

// ---------------------------------------------------------------- fused front-end
__global__ __launch_bounds__(512) void k_front(
    const float* __restrict__ x, const float* __restrict__ kw,
    const float* __restrict__ ow1, const float* __restrict__ ob1,
    const float* __restrict__ ow2, const float* __restrict__ ob2,
    u32* __restrict__ xpad, u32* __restrict__ w2,
    int* __restrict__ cnt, int* __restrict__ list) {
  __shared__ float red[8][64][9];   // stride-9 dwords -> 2-way bank alias (free)
  __shared__ int lcnt[9], lbase[9];

  int bid = blockIdx.x;
  int tid = threadIdx.x;

  if (bid < 392) {
    // ---------------- observer + argmax + compaction (64 px x 8 d-groups)
    int px = tid & 63;
    int dg = tid >> 6;
    int dgu = __builtin_amdgcn_readfirstlane(dg);   // provably wave-uniform
    int pix = bid * 64 + px;        // block stays within one b (3136 % 64 == 0)
    int b = pix / 3136, s = pix - b * 3136;
    const float* xb = x + (size_t)b * 401408 + s;

    if (tid < 9) lcnt[tid] = 0;

    float h[16];
    const float* o1 = ob1 + dgu * 16;               // scalar loads
#pragma unroll
    for (int i = 0; i < 16; ++i) h[i] = o1[i];

    const float* w1b = ow1 + dgu * 16 * 128;        // row block, uniform base
    for (int cc = 0; cc < 128; cc += 8) {           // only dynamic loop
      float xc[8];
#pragma unroll
      for (int j = 0; j < 8; ++j) xc[j] = xb[(size_t)(cc + j) * 3136];
#pragma unroll
      for (int i = 0; i < 16; ++i) {
        const float* wr = w1b + i * 128 + cc;       // uniform -> s_load_dwordx8
        float a = h[i];
#pragma unroll
        for (int j = 0; j < 8; ++j) a = fmaf(wr[j], xc[j], a);
        h[i] = a;
      }
    }

#pragma unroll
    for (int i = 0; i < 16; ++i) h[i] = tanhf(h[i]);

#pragma unroll
    for (int p = 0; p < 9; ++p) {
      float sc = 0.f;
      const float* wr = ow2 + p * 128 + dgu * 16;   // scalar loads
#pragma unroll
      for (int i = 0; i < 16; ++i) sc = fmaf(wr[i], h[i], sc);
      red[dg][px][p] = sc;
    }
    __syncthreads();

    int bi = 0, slot = 0;
    if (dg == 0) {
      float best = 0.f;
#pragma unroll
      for (int p = 0; p < 9; ++p) {
        float v = ob2[p];
#pragma unroll
        for (int g = 0; g < 8; ++g) v += red[g][px][p];  // ascending-d order
        if (p == 0 || v > best) { best = v; bi = p; }    // strict >: np argmax
      }
      slot = atomicAdd(&lcnt[bi], 1);   // LDS atomic
    }
    __syncthreads();
    if (tid < 9) lbase[tid] = atomicAdd(&cnt[tid], lcnt[tid]);
    __syncthreads();
    if (dg == 0) list[bi * NPIX + lbase[bi] + slot] = pix;

  } else if (bid < 840) {
    // ---------------- x (NCHW f32) -> x_pad (N,58,58,CI) bf16, rows 1..56
    int bh = bid - 392;                  // 0..447 = b*56+h
    int b = bh / 56, hh = bh - b * 56;
    int cp = tid & 63;                   // ci pair
    int wq = tid >> 6;                   // 8 w-lanes
    const float* xb = x + (size_t)(b * 128 + 2 * cp) * 3136 + hh * 56;
    u32* orow = xpad + (size_t)(b * 58 + hh + 1) * 58 * 64;
    for (int w = wq; w < 56; w += 8) {
      float f0 = xb[w];
      float f1 = xb[3136 + w];
      orow[(w + 1) * 64 + cp] = (u32)f2bf(f0) | ((u32)f2bf(f1) << 16);
    }
    if (wq == 0) orow[cp] = 0;                // halo col 0
    else if (wq == 1) orow[57 * 64 + cp] = 0; // halo col 57

  } else if (bid < 856) {
    // ---------------- zero halo rows h=0 and h=57 per b
    int r = bid - 840;                   // 0..15
    int b = r >> 1;
    u32* orow = xpad + ((size_t)(b * 58) + ((r & 1) ? 57 : 0)) * 58 * 64;
    for (int i = tid; i < 58 * 64; i += 512) orow[i] = 0;

  } else {
    // ---------------- kw (P,CO,CI,3,3) f32 -> W2 (P,CO,1152) bf16, grid-stride
    for (int t = (bid - 856) * 512 + tid; t < 1327104; t += 256 * 512) {
      int cp = t & 63;
      int r = t >> 6;             // pco*9 + tap
      int tap = r % 9;
      int pco = r / 9;
      const float* sp = kw + ((size_t)pco * 128 + 2 * cp) * 9 + tap;
      w2[t] = (u32)f2bf(sp[0]) | ((u32)f2bf(sp[9]) << 16);
    }
  }
}

// ---------------------------------------------------------------- gathered GEMM conv
__global__ __launch_bounds__(256, 3) void k_conv(
    const int* __restrict__ cnt, const int* __restrict__ list,
    const char* __restrict__ xpadB, const char* __restrict__ w2B,
    const float* __restrict__ kb, float* __restrict__ out) {
  __shared__ short Wlds[2][4096];  // [buf][co(128) x k(32)]
  __shared__ short Plds[2][4096];  // [buf][px(128) x k(32)]
  __shared__ int offsB[128], outSB[128];
  __shared__ float kbl[128];

  int bid = blockIdx.x;
  int half = bid & 1, tb = bid >> 1;
  int p = -1, cntp = 0;
  for (int pp = 0; pp < 9; ++pp) {     // uniform scan: block -> (path, tile)
    int c = cnt[pp];
    int tt = (c + 127) >> 7;
    if (p < 0) {
      if (tb < tt) { p = pp; cntp = c; }
      else tb -= tt;
    }
  }
  if (p < 0) return;
  int nbase = tb * 128;
  int tid = threadIdx.x;

  if (tid < 128) {
    int g = nbase + tid;
    int pixid = list[p * NPIX + (g < cntp ? g : nbase)];
    int b = pixid / 3136, s = pixid - b * 3136;
    int h = s / 56, w = s - h * 56;
    offsB[tid] = ((b * 58 + h) * 58 + w) * 256;  // byte offset of tap(0,0) in x_pad
    outSB[tid] = b * 802816 + s;
    kbl[tid] = kb[p * 256 + half * 128 + tid];
  }
  __syncthreads();

  int seg16 = (tid & 3) * 16;
  int na = tid >> 2;                       // 0..63
  int offP0 = offsB[na] + seg16;
  int offP1 = offsB[64 + na] + seg16;
  const char* wrow = w2B + (size_t)(p * 256 + half * 128) * 2304;
  const char* wp0 = wrow + na * 2304 + seg16;
  const char* wp1 = wrow + (size_t)(64 + na) * 2304 + seg16;

  auto stage = [&](int c, int q) {
    int tap = c >> 2, kc = c & 3;
    int wko = tap * 256 + kc * 64;                          // bytes within W row
    int tapoff = ((tap / 3) * 58 + (tap % 3)) * 256 + kc * 64;  // bytes within x_pad
    GLDS16(wp0 + wko, &Wlds[q][tid * 8]);
    GLDS16(wp1 + wko, &Wlds[q][2048 + tid * 8]);
    GLDS16(xpadB + (size_t)(offP0 + tapoff), &Plds[q][tid * 8]);
    GLDS16(xpadB + (size_t)(offP1 + tapoff), &Plds[q][2048 + tid * 8]);
  };

  f32x4 acc[4][4];
#pragma unroll
  for (int mt = 0; mt < 4; ++mt)
#pragma unroll
    for (int nt = 0; nt < 4; ++nt) acc[mt][nt] = (f32x4)0.f;

  int lane = tid & 63, wave = tid >> 6;
  int wm = wave >> 1, wn = wave & 1;
  int mrow = wm * 64 + (lane & 15);
  int nrow = wn * 64 + (lane & 15);
  int kg8 = (lane >> 4) * 8;

  stage(0, 0);
  for (int c = 0; c < 36; ++c) {
    __syncthreads();                       // drains stage(c); protects buffer reuse
    if (c + 1 < 36) stage(c + 1, (c + 1) & 1);
    int q = c & 1;
    bf16x8 af[4], bfr[4];
#pragma unroll
    for (int mt = 0; mt < 4; ++mt)
      af[mt] = *(const bf16x8*)&Wlds[q][(mrow + mt * 16) * 32 + kg8];
#pragma unroll
    for (int nt = 0; nt < 4; ++nt)
      bfr[nt] = *(const bf16x8*)&Plds[q][(nrow + nt * 16) * 32 + kg8];
#pragma unroll
    for (int mt = 0; mt < 4; ++mt)
#pragma unroll
      for (int nt = 0; nt < 4; ++nt)
        acc[mt][nt] = __builtin_amdgcn_mfma_f32_16x16x32_bf16(
            af[mt], bfr[nt], acc[mt][nt], 0, 0, 0);
  }

  // epilogue: D col = lane&15 (pixel), row = (lane>>4)*4 + r (co)
  int col = lane & 15, quad = lane >> 4;
#pragma unroll
  for (int nt = 0; nt < 4; ++nt) {
    int n = wn * 64 + nt * 16 + col;
    bool valid = (nbase + n) < cntp;
    int ob = outSB[n];
#pragma unroll
    for (int mt = 0; mt < 4; ++mt) {
#pragma unroll
      for (int r = 0; r < 4; ++r) {
        int co_l = wm * 64 + mt * 16 + quad * 4 + r;
        float v = acc[mt][nt][r] + kbl[co_l];
        v = v > 0.f ? v : 0.f;
        if (valid) out[ob + (half * 128 + co_l) * 3136] = v;
      }
    }
  }
}

// ----------------------------------------------------------------
extern "C" void kernel_launch(void* const* d_in, const int* in_sizes, int n_in,
                              void* d_out, int out_size, void* d_ws, size_t ws_size,
                              hipStream_t stream) {
  const float* x   = (const float*)d_in[0];
  const float* kw  = (const float*)d_in[1];
  const float* kb  = (const float*)d_in[2];
  const float* ow1 = (const float*)d_in[3];
  const float* ob1 = (const float*)d_in[4];
  const float* ow2 = (const float*)d_in[5];
  const float* ob2 = (const float*)d_in[6];
  float* out = (float*)d_out;
  char* ws = (char*)d_ws;

  int* cnt  = (int*)(ws);
  int* list = (int*)(ws + OFF_LIST);
  u32* xpad = (u32*)(ws + OFF_XPAD);
  u32* w2   = (u32*)(ws + OFF_W2);

  hipMemsetAsync(cnt, 0, 64, stream);  // must precede k_front (obs atomics)

  k_front<<<1112, 512, 0, stream>>>(x, kw, ow1, ob1, ow2, ob2, xpad, w2,
                                    cnt, list);
  k_conv<<<408, 256, 0, stream>>>(cnt, list, (const char*)xpad, (const char*)w2,
                                  kb, out);
}

// Round 6
// 165.438 us; speedup vs baseline: 6.1542x; 1.0944x over previous
//
#include <hip/hip_runtime.h>
#include <hip/hip_bf16.h>

// ProbableConv2d: selection-first implementation.
// B=8, CI=128, CO=256, H=W=56, P=9, K=3.
//
// 4 dispatches:
//   memset cnt (64 B)
//   k_front : fused — [obs 0..391] fp32 observer -> argmax -> per-path lists;
//             [392..839] x -> x_pad NHWC bf16; [840..855] halo rows;
//             [856..1111] kw -> W2 bf16.
//   k_conv  : per (path, co-half, 64-px tile) gathered-GEMM, MFMA bf16.
//             R6: writes compact outc[slot][co] bf16 (+pix2row) instead of
//             scattering into NCHW — R5 epilogue scatter cost 137 MB of HBM
//             writes (5.4x ampl., cross-XCD partial lines) = the 70us.
//             Also: N tile 128->64 (802 blocks, was 408 @ 12.6% occupancy) and
//             XOR k-segment swizzle (8-way ds_read_b128 conflicts -> 2-way).
//   k_out   : output-ordered scatter-free writer: lanes = consecutive s,
//             gathered outc reads, coalesced 256 B NCHW stores.

typedef unsigned int u32;

#define NPIX    25088      // 8*56*56
#define OFF_LIST 4096
#define OFF_XPAD 907264                      // 4096 + 9*25088*4
#define OFF_W2   7796736                     // + 8*58*58*128*2
#define OFF_P2R  13105152                    // + 1327104*4
#define OFF_OUTC 13205504                    // + 25088*4   (outc: 25088*256*2 B)

__device__ __forceinline__ unsigned short f2bf(float f) {
  u32 u = __builtin_bit_cast(u32, f);
  u32 r = (u + 0x7FFFu + ((u >> 16) & 1u)) >> 16;
  return (unsigned short)r;
}
__device__ __forceinline__ float bflo(u32 w) {
  return __builtin_bit_cast(float, w << 16);
}
__device__ __forceinline__ float bfhi(u32 w) {
  return __builtin_bit_cast(float, w & 0xFFFF0000u);
}

#define GLDS16(g, l)                                                        \
  __builtin_amdgcn_global_load_lds(                                         \
      (const __attribute__((address_space(1))) u32*)(g),                    \
      (__attribute__((address_space(3))) u32*)(l), 16, 0, 0)

typedef __attribute__((ext_vector_type(8))) short bf16x8;
typedef __attribute__((ext_vector_type(4))) float f32x4;

// ---------------------------------------------------------------- fused front-end
__global__ __launch_bounds__(512) void k_front(
    const float* __restrict__ x, const float* __restrict__ kw,
    const float* __restrict__ ow1, const float* __restrict__ ob1,
    const float* __restrict__ ow2, const float* __restrict__ ob2,
    u32* __restrict__ xpad, u32* __restrict__ w2,
    int* __restrict__ cnt, int* __restrict__ list) {
  __shared__ float red[8][64][9];   // stride-9 dwords -> 2-way bank alias (free)
  __shared__ int lcnt[9], lbase[9];

  int bid = blockIdx.x;
  int tid = threadIdx.x;

  if (bid < 392) {
    // ---------------- observer + argmax + compaction (64 px x 8 d-groups)
    int px = tid & 63;
    int dg = tid >> 6;
    int dgu = __builtin_amdgcn_readfirstlane(dg);   // provably wave-uniform
    int pix = bid * 64 + px;        // block stays within one b (3136 % 64 == 0)
    int b = pix / 3136, s = pix - b * 3136;
    const float* xb = x + (size_t)b * 401408 + s;

    if (tid < 9) lcnt[tid] = 0;

    float h[16];
    const float* o1 = ob1 + dgu * 16;               // scalar loads
#pragma unroll
    for (int i = 0; i < 16; ++i) h[i] = o1[i];

    const float* w1b = ow1 + dgu * 16 * 128;        // row block, uniform base
    for (int cc = 0; cc < 128; cc += 8) {           // only dynamic loop
      float xc[8];
#pragma unroll
      for (int j = 0; j < 8; ++j) xc[j] = xb[(size_t)(cc + j) * 3136];
#pragma unroll
      for (int i = 0; i < 16; ++i) {
        const float* wr = w1b + i * 128 + cc;       // uniform -> s_load_dwordx8
        float a = h[i];
#pragma unroll
        for (int j = 0; j < 8; ++j) a = fmaf(wr[j], xc[j], a);
        h[i] = a;
      }
    }

#pragma unroll
    for (int i = 0; i < 16; ++i) h[i] = tanhf(h[i]);

#pragma unroll
    for (int p = 0; p < 9; ++p) {
      float sc = 0.f;
      const float* wr = ow2 + p * 128 + dgu * 16;   // scalar loads
#pragma unroll
      for (int i = 0; i < 16; ++i) sc = fmaf(wr[i], h[i], sc);
      red[dg][px][p] = sc;
    }
    __syncthreads();

    int bi = 0, slot = 0;
    if (dg == 0) {
      float best = 0.f;
#pragma unroll
      for (int p = 0; p < 9; ++p) {
        float v = ob2[p];
#pragma unroll
        for (int g = 0; g < 8; ++g) v += red[g][px][p];  // ascending-d order
        if (p == 0 || v > best) { best = v; bi = p; }    // strict >: np argmax
      }
      slot = atomicAdd(&lcnt[bi], 1);   // LDS atomic
    }
    __syncthreads();
    if (tid < 9) lbase[tid] = atomicAdd(&cnt[tid], lcnt[tid]);
    __syncthreads();
    if (dg == 0) list[bi * NPIX + lbase[bi] + slot] = pix;

  } else if (bid < 840) {
    // ---------------- x (NCHW f32) -> x_pad (N,58,58,CI) bf16, rows 1..56
    int bh = bid - 392;                  // 0..447 = b*56+h
    int b = bh / 56, hh = bh - b * 56;
    int cp = tid & 63;                   // ci pair
    int wq = tid >> 6;                   // 8 w-lanes
    const float* xb = x + (size_t)(b * 128 + 2 * cp) * 3136 + hh * 56;
    u32* orow = xpad + (size_t)(b * 58 + hh + 1) * 58 * 64;
    for (int w = wq; w < 56; w += 8) {
      float f0 = xb[w];
      float f1 = xb[3136 + w];
      orow[(w + 1) * 64 + cp] = (u32)f2bf(f0) | ((u32)f2bf(f1) << 16);
    }
    if (wq == 0) orow[cp] = 0;                // halo col 0
    else if (wq == 1) orow[57 * 64 + cp] = 0; // halo col 57

  } else if (bid < 856) {
    // ---------------- zero halo rows h=0 and h=57 per b
    int r = bid - 840;                   // 0..15
    int b = r >> 1;
    u32* orow = xpad + ((size_t)(b * 58) + ((r & 1) ? 57 : 0)) * 58 * 64;
    for (int i = tid; i < 58 * 64; i += 512) orow[i] = 0;

  } else {
    // ---------------- kw (P,CO,CI,3,3) f32 -> W2 (P,CO,1152) bf16, grid-stride
    for (int t = (bid - 856) * 512 + tid; t < 1327104; t += 256 * 512) {
      int cp = t & 63;
      int r = t >> 6;             // pco*9 + tap
      int tap = r % 9;
      int pco = r / 9;
      const float* sp = kw + ((size_t)pco * 128 + 2 * cp) * 9 + tap;
      w2[t] = (u32)f2bf(sp[0]) | ((u32)f2bf(sp[9]) << 16);
    }
  }
}

// ---------------------------------------------------------------- gathered GEMM conv
__global__ __launch_bounds__(256, 4) void k_conv(
    const int* __restrict__ cnt, const int* __restrict__ list,
    const char* __restrict__ xpadB, const char* __restrict__ w2B,
    const float* __restrict__ kb, unsigned short* __restrict__ outcH,
    int* __restrict__ pix2row) {
  __shared__ short Wlds[2][4096];  // [buf][co(128) x k(32)], k-seg XOR-swizzled
  __shared__ short Plds[2][2048];  // [buf][px(64) x k(32)],  k-seg XOR-swizzled
  __shared__ int offsB[64];
  __shared__ float kbl[128];

  int bid = blockIdx.x;
  int half = bid & 1, tb = bid >> 1;
  int p = -1, cntp = 0, baseP = 0, accb = 0;
  for (int pp = 0; pp < 9; ++pp) {     // uniform scan: block -> (path, tile)
    int c = cnt[pp];
    int tt = (c + 63) >> 6;
    if (p < 0) {
      if (tb < tt) { p = pp; cntp = c; baseP = accb; }
      else tb -= tt;
    }
    accb += c;
  }
  if (p < 0) return;
  int nbase = tb * 64;
  int tid = threadIdx.x;

  if (tid < 64) {
    int g = nbase + tid;
    bool v = g < cntp;
    int pixid = list[p * NPIX + (v ? g : nbase)];
    int b = pixid / 3136, s = pixid - b * 3136;
    int h = s / 56, w = s - h * 56;
    offsB[tid] = ((b * 58 + h) * 58 + w) * 256;  // byte offset of tap(0,0)
    if (v && half == 0) pix2row[pixid] = baseP + g;
  }
  if (tid < 128) kbl[tid] = kb[p * 256 + half * 128 + tid];
  __syncthreads();

  // stage: LDS slot s of row r holds global k-segment s ^ ((r>>1)&3)
  int segsw = ((tid & 3) ^ ((tid >> 3) & 3)) * 16;   // byte offset of segment
  int na = tid >> 2;                                 // row 0..63
  int offP = offsB[na] + segsw;
  const char* wrow = w2B + (size_t)(p * 256 + half * 128) * 2304;
  const char* wp0 = wrow + (size_t)na * 2304 + segsw;
  const char* wp1 = wrow + (size_t)(64 + na) * 2304 + segsw;

  auto stage = [&](int c, int q) {
    int tap = c >> 2, kc = c & 3;
    int wko = tap * 256 + kc * 64;                          // bytes in W row
    int tapoff = ((tap / 3) * 58 + (tap % 3)) * 256 + kc * 64;  // bytes in x_pad
    GLDS16(wp0 + wko, &Wlds[q][tid * 8]);
    GLDS16(wp1 + wko, &Wlds[q][2048 + tid * 8]);
    GLDS16(xpadB + (size_t)(offP + tapoff), &Plds[q][tid * 8]);
  };

  f32x4 acc[4][2];
#pragma unroll
  for (int mt = 0; mt < 4; ++mt)
#pragma unroll
    for (int nt = 0; nt < 2; ++nt) acc[mt][nt] = (f32x4)0.f;

  int lane = tid & 63, wave = tid >> 6;
  int wm = wave >> 1, wn = wave & 1;
  int l15 = lane & 15, quad = lane >> 4;
  int slot = (quad ^ ((l15 >> 1) & 3)) * 8;   // swizzled k-segment (shorts)
  int mrow = wm * 64 + l15;
  int nrow = wn * 32 + l15;

  stage(0, 0);
  for (int c = 0; c < 36; ++c) {
    __syncthreads();                       // drains stage(c); protects reuse
    if (c + 1 < 36) stage(c + 1, (c + 1) & 1);
    int q = c & 1;
    bf16x8 af[4], bfr[2];
#pragma unroll
    for (int mt = 0; mt < 4; ++mt)
      af[mt] = *(const bf16x8*)&Wlds[q][(mrow + mt * 16) * 32 + slot];
#pragma unroll
    for (int nt = 0; nt < 2; ++nt)
      bfr[nt] = *(const bf16x8*)&Plds[q][(nrow + nt * 16) * 32 + slot];
#pragma unroll
    for (int mt = 0; mt < 4; ++mt)
#pragma unroll
      for (int nt = 0; nt < 2; ++nt)
        acc[mt][nt] = __builtin_amdgcn_mfma_f32_16x16x32_bf16(
            af[mt], bfr[nt], acc[mt][nt], 0, 0, 0);
  }

  // epilogue: D col = lane&15 (pixel), row = quad*4 + r (co) -> compact outc
#pragma unroll
  for (int nt = 0; nt < 2; ++nt) {
    int n = wn * 32 + nt * 16 + l15;
    if ((nbase + n) >= cntp) continue;
    size_t rowb = (size_t)(baseP + nbase + n) * 256 + half * 128;
#pragma unroll
    for (int mt = 0; mt < 4; ++mt) {
      int co0 = wm * 64 + mt * 16 + quad * 4;
      float v0 = acc[mt][nt][0] + kbl[co0 + 0];
      float v1 = acc[mt][nt][1] + kbl[co0 + 1];
      float v2 = acc[mt][nt][2] + kbl[co0 + 2];
      float v3 = acc[mt][nt][3] + kbl[co0 + 3];
      v0 = v0 > 0.f ? v0 : 0.f;  v1 = v1 > 0.f ? v1 : 0.f;
      v2 = v2 > 0.f ? v2 : 0.f;  v3 = v3 > 0.f ? v3 : 0.f;
      u32 lo = (u32)f2bf(v0) | ((u32)f2bf(v1) << 16);
      u32 hi = (u32)f2bf(v2) | ((u32)f2bf(v3) << 16);
      *(u32*)&outcH[rowb + co0]     = lo;
      *(u32*)&outcH[rowb + co0 + 2] = hi;
    }
  }
}

// ---------------------------------------------------------------- output-ordered writer
__global__ __launch_bounds__(256) void k_out(
    const int* __restrict__ pix2row, const u32* __restrict__ outcU,
    float* __restrict__ out) {
  int tid = threadIdx.x;
  int pl = tid & 63, coq = tid >> 6;       // wave-uniform co quarter
  int pix = blockIdx.x * 64 + pl;          // lanes = consecutive s
  int b = pix / 3136, s = pix - b * 3136;
  int row = pix2row[pix];
  const u32* src = outcU + (size_t)row * 128 + coq * 32;
  float* dst = out + (size_t)b * 802816 + s;
#pragma unroll
  for (int j = 0; j < 8; ++j) {
    uint4 w = *(const uint4*)(src + j * 4);   // 8 co values (bf16 pairs)
    int co = coq * 64 + j * 8;
    dst[(size_t)(co + 0) * 3136] = bflo(w.x);
    dst[(size_t)(co + 1) * 3136] = bfhi(w.x);
    dst[(size_t)(co + 2) * 3136] = bflo(w.y);
    dst[(size_t)(co + 3) * 3136] = bfhi(w.y);
    dst[(size_t)(co + 4) * 3136] = bflo(w.z);
    dst[(size_t)(co + 5) * 3136] = bfhi(w.z);
    dst[(size_t)(co + 6) * 3136] = bflo(w.w);
    dst[(size_t)(co + 7) * 3136] = bfhi(w.w);
  }
}

// ----------------------------------------------------------------
extern "C" void kernel_launch(void* const* d_in, const int* in_sizes, int n_in,
                              void* d_out, int out_size, void* d_ws, size_t ws_size,
                              hipStream_t stream) {
  const float* x   = (const float*)d_in[0];
  const float* kw  = (const float*)d_in[1];
  const float* kb  = (const float*)d_in[2];
  const float* ow1 = (const float*)d_in[3];
  const float* ob1 = (const float*)d_in[4];
  const float* ow2 = (const float*)d_in[5];
  const float* ob2 = (const float*)d_in[6];
  float* out = (float*)d_out;
  char* ws = (char*)d_ws;

  int* cnt  = (int*)(ws);
  int* list = (int*)(ws + OFF_LIST);
  u32* xpad = (u32*)(ws + OFF_XPAD);
  u32* w2   = (u32*)(ws + OFF_W2);
  int* p2r  = (int*)(ws + OFF_P2R);
  unsigned short* outc = (unsigned short*)(ws + OFF_OUTC);

  hipMemsetAsync(cnt, 0, 64, stream);  // must precede k_front (obs atomics)

  k_front<<<1112, 512, 0, stream>>>(x, kw, ow1, ob1, ow2, ob2, xpad, w2,
                                    cnt, list);
  k_conv<<<802, 256, 0, stream>>>(cnt, list, (const char*)xpad, (const char*)w2,
                                  kb, outc, p2r);
  k_out<<<392, 256, 0, stream>>>(p2r, (const u32*)outc, out);
}